// Round 13
// baseline (612.505 us; speedup 1.0000x reference)
//
#include <hip/hip_runtime.h>
#include <hip/hip_bf16.h>

// CSMultiHeadAttention. B=8, S=3072 (3x1024), E=512, H=8, d=64.
// fp32 I/O, bf16 workspace, fp32 MFMA accumulate.
// R7-R15 (VERIFIED, 256.0us): attn in-reg P (permlane transpose), T5 setprio,
//   KVBLK=128 single-buffer; qkv/proj single-buffer + T1 XCD swizzle.
// R16 (VERIFIED, 252.2us): conv merged to one launch; boundary cost ~3.8us.
// R18 (this round): qkv/proj tile 128x128 -> 256x128 (tokens x f), BK=64,
//   8 waves/block. Theory: qkv is L2-staging-BW-bound (per step: 32KB staged
//   vs 640cyc MFMA/CU -> ratio 3.6:1 -> MfmaUtil 21% measured ✓). 256-token
//   tile stages 48KB per step for 2x output -> +33% MFMA/byte. LDS 48KB,
//   acc stays 4x4/wave (VGPR ~124, capped by __launch_bounds__(512,4)).
//   Wave split: xo=(w&3)*64 tokens, fo=(w>>2)*64 f. Grids: qkv 1152=96x12,
//   proj 384=96x4 (XCD-chunked, bijective). attn/conv byte-identical.
// MFMA 16x16x32 bf16. A/B frag: [m|n = lane&15][k = (lane>>4)*8 + j].
// C/D: col = lane&15, row = (lane>>4)*4 + reg.
// GEMM LDS tiles XOR-swizzled (block kb ^ (row&7)): free 2-way banks AND
// matches global_load_lds lane-contiguous destination.

typedef __attribute__((ext_vector_type(8))) short short8v;     // 8 bf16 (4 VGPR)
typedef __attribute__((ext_vector_type(4))) float float4v;
typedef __attribute__((ext_vector_type(4))) unsigned short ushort4v;
typedef __attribute__((ext_vector_type(4))) unsigned int uint4v;

#define CHUNKS 3
#define BATCH 8
#define SEQ 3072
#define EMB 512
#define NH 8
#define HD 64
#define NCK 1024
#define MTOT (BATCH*SEQ)                      // 24576
#define QKV_ELEMS (CHUNKS*BATCH*NH*NCK*HD)    // 12582912 (== x elem count)
#define WELEMS (CHUNKS*EMB*EMB)               // 786432 per weight tensor
#define XCONV_BLOCKS (QKV_ELEMS / (256 * 8))  // 6144
#define WCONV_BLOCKS (WELEMS / (256 * 8))     // 384 per weight tensor
// 1/sqrt(512) * log2(e): softmax exp folded to exp2
#define QSCALE 0.06375872465f

__device__ __forceinline__ unsigned short f2b(float f) {
  union { float f; unsigned int i; } x; x.f = f;
  unsigned int r = x.i + 0x7FFFu + ((x.i >> 16) & 1u);  // RNE
  return (unsigned short)(r >> 16);
}
// pack two fp32 -> two bf16 (round-half-up) in 3 VALU via v_perm
__device__ __forceinline__ unsigned int pack2r(float a, float b) {
  union { float f; unsigned int u; } xa, xb; xa.f = a; xb.f = b;
  return __builtin_amdgcn_perm(xb.u + 0x8000u, xa.u + 0x8000u, 0x07060302u);
}
__device__ __forceinline__ void gld_lds16(const unsigned short* g, unsigned short* l) {
  __builtin_amdgcn_global_load_lds(
      (const __attribute__((address_space(1))) unsigned int*)g,
      (__attribute__((address_space(3))) unsigned int*)l, 16, 0, 0);
}
#define MFMA(a, b, c) __builtin_amdgcn_mfma_f32_16x16x32_bf16(a, b, c, 0, 0, 0)

// ---------------- fp32 -> bf16 conversion (streaming, single launch) -------
// Blocks [0, XCONV_BLOCKS): convert x -> xbf.
// Blocks [XCONV_BLOCKS, +4*WCONV_BLOCKS): convert Wq/Wk/Wv/Wp -> Wb.
__global__ __launch_bounds__(256) void conv_all(
    const float* __restrict__ x,
    const float* __restrict__ s0, const float* __restrict__ s1,
    const float* __restrict__ s2, const float* __restrict__ s3,
    unsigned short* __restrict__ xbf, unsigned short* __restrict__ Wb)
{
  const int bid = blockIdx.x;
  const float* src;
  unsigned short* dst;
  size_t i;
  if (bid < XCONV_BLOCKS) {
    i = ((size_t)bid * 256 + threadIdx.x) * 8;
    src = x;
    dst = xbf;
  } else {
    const int wb = bid - XCONV_BLOCKS;
    const int z = wb / WCONV_BLOCKS;
    i = ((size_t)(wb % WCONV_BLOCKS) * 256 + threadIdx.x) * 8;
    src = (z == 0) ? s0 : (z == 1) ? s1 : (z == 2) ? s2 : s3;
    dst = Wb + (size_t)z * WELEMS;
  }
  float4 a = *(const float4*)&src[i];
  float4 b = *(const float4*)&src[i + 4];
  uint4v p;
  p[0] = pack2r(a.x, a.y); p[1] = pack2r(a.z, a.w);
  p[2] = pack2r(b.x, b.y); p[3] = pack2r(b.z, b.w);
  *(uint4v*)&dst[i] = p;
}

// ---------------- QKV projection ----------------
// 256x128 tile (tokens x f), BK=64, 8 waves: wave w owns tokens
// xo=(w&3)*64, f-cols fo=(w>>2)*64; acc 4x4 per wave. LDS 48KB single-buf.
// 1D grid 1152, T1 XCD-chunk swizzle: lin=(bid&7)*144+bid/8;
// col0=(lin&3)*128, z=(lin>>2)%3, row0=(lin/12)*256. x-panel sharers
// (4 col x 3 z = 12) consecutive within an XCD chunk.
// z<=1 (Q,K): D = W·X^T -> [f][token] -> packed b64 stores along d into [n][d].
//             Q is additionally scaled by QSCALE (softmax scale * log2e).
// z==2 (V):   D = X·W^T -> [token][f] -> packed b64 stores along n into [d][n].
__global__ __launch_bounds__(512, 4) void qkv_gemm(
    const unsigned short* __restrict__ xb, const unsigned short* __restrict__ Wb,
    const float* __restrict__ bq, const float* __restrict__ bk,
    const float* __restrict__ bv,
    unsigned short* __restrict__ qt, unsigned short* __restrict__ kt,
    unsigned short* __restrict__ vt)
{
  const int tid = threadIdx.x;
  const int w = tid >> 6, l = tid & 63;
  const int ln = l & 15, qu = l >> 4;
  const int sr = l >> 3, kbl = l & 7;
  const int bid = blockIdx.x;
  const int lin = (bid & 7) * 144 + (bid >> 3);
  const int col0 = (lin & 3) * 128;
  const int z = (lin >> 2) % 3;
  const int row0 = (lin / 12) * 256;
  const int bglob = row0 / SEQ;
  const int c = (row0 % SEQ) / NCK;
  const int n0 = row0 % NCK;
  const unsigned short* W = Wb + (size_t)z * WELEMS + c * EMB * EMB;
  const float* bias = (z == 0 ? bq : (z == 1 ? bk : bv)) + c * EMB;
  const float oscale = (z == 0) ? QSCALE : 1.0f;

  __shared__ unsigned short As[256 * 64];   // x-tile, swizzled, 32KB
  __shared__ unsigned short Bs[128 * 64];   // W-tile, swizzled, 16KB

  const int xo = (w & 3) * 64, fo = (w >> 2) * 64;

  float4v acc[4][4];
#pragma unroll
  for (int i = 0; i < 4; ++i)
#pragma unroll
    for (int j = 0; j < 4; ++j) acc[i][j] = (float4v){0.f, 0.f, 0.f, 0.f};

  for (int k0 = 0; k0 < EMB; k0 += 64) {
    __syncthreads();
    {
      int kb_g = kbl ^ sr;                   // swizzled k-block
#pragma unroll
      for (int s = 0; s < 4; ++s) {          // As: 256 rows, 32/wave
        int rbase = w * 32 + s * 8;
        gld_lds16(&xb[(size_t)(row0 + rbase + sr) * EMB + k0 + kb_g * 8],
                  &As[rbase * 64]);
      }
#pragma unroll
      for (int s = 0; s < 2; ++s) {          // Bs: 128 rows, 16/wave
        int rbase = w * 16 + s * 8;
        gld_lds16(&W[(size_t)(col0 + rbase + sr) * EMB + k0 + kb_g * 8],
                  &Bs[rbase * 64]);
      }
    }
    __syncthreads();
#pragma unroll
    for (int ks = 0; ks < 2; ++ks) {
      short8v xf[4], wf[4];
#pragma unroll
      for (int i = 0; i < 4; ++i) {
        int rx = xo + 16 * i + ln;
        xf[i] = *(const short8v*)&As[rx * 64 + (((ks * 4 + qu) ^ (rx & 7)) * 8)];
        int rw = fo + 16 * i + ln;
        wf[i] = *(const short8v*)&Bs[rw * 64 + (((ks * 4 + qu) ^ (rw & 7)) * 8)];
      }
      if (z <= 1) {
#pragma unroll
        for (int i = 0; i < 4; ++i)
#pragma unroll
          for (int j = 0; j < 4; ++j) acc[i][j] = MFMA(wf[j], xf[i], acc[i][j]);
      } else {
#pragma unroll
        for (int i = 0; i < 4; ++i)
#pragma unroll
          for (int j = 0; j < 4; ++j) acc[i][j] = MFMA(xf[i], wf[j], acc[i][j]);
      }
    }
  }

  if (z <= 1) {
    unsigned short* outp = (z == 0) ? qt : kt;
#pragma unroll
    for (int j = 0; j < 4; ++j) {            // f (M side)
      int f0 = col0 + fo + 16 * j + 4 * qu;  // + r
      float4 b4 = *(const float4*)&bias[f0];
      int hh = f0 >> 6, dd0 = f0 & 63;
      size_t base = ((size_t)((c * 8 + bglob) * 8 + hh)) << 16;
#pragma unroll
      for (int i = 0; i < 4; ++i) {          // token (N side)
        int n = n0 + xo + 16 * i + ln;
        ushort4v p;
#pragma unroll
        for (int r = 0; r < 4; ++r)
          p[r] = f2b((acc[i][j][r] + ((const float*)&b4)[r]) * oscale);
        *(ushort4v*)&outp[base + (size_t)n * 64 + dd0] = p;
      }
    }
  } else {
#pragma unroll
    for (int i = 0; i < 4; ++i) {            // token (M side)
      int nn0 = n0 + xo + 16 * i + 4 * qu;   // + r
#pragma unroll
      for (int j = 0; j < 4; ++j) {          // f (N side)
        int f = col0 + fo + 16 * j + ln;
        int hh = f >> 6, dd = f & 63;
        float bvv = bias[f];
        size_t base = ((size_t)((c * 8 + bglob) * 8 + hh)) << 16;
        ushort4v p;
#pragma unroll
        for (int r = 0; r < 4; ++r) p[r] = f2b(acc[i][j][r] + bvv);
        *(ushort4v*)&vt[base + (size_t)dd * 1024 + nn0] = p;
      }
    }
  }
}

// ---------------- Attention (flash, MFMA) ----------------
// 512 threads / 8 waves / 256 q rows per block; 4 q-blocks per head.
// SINGLE-buffered, KVBLK=128 (VERIFIED 69.4us): one barrier pair stages 128
// keys (Ks[128][64], Vs[2][64][64], 32KB), then TWO 64-key sub-passes.
// Per sub-pass: S^T = K·Q^T (ks=0 literal-zero C); per 32-key half: exp2 ->
// pack2r -> permlane 4x4 transpose -> denom(ones-MFMA) + O^T += V^T·P^T.
// Q pre-scaled by 1/sqrt(512)*log2e in qkv -> raw v_exp_f32 here.
// setprio(1) wraps MFMA clusters (T5).
//
// P redistribution: S^T C/D gives lane(ln,qu) S[q=ln][key=16mt+4qu+r];
// PV B-frag needs P[q=ln][key=8qu+j]. permlane32_swap x2 (l5<->mh) then
// permlane16_swap x2 (l4<->old l5); frag = [m00,m01,m10,m11].
// (VERIFIED on HW: absmax 4.9e-4.)
__global__ __launch_bounds__(512) void attn_kernel(
    const unsigned short* __restrict__ qt,
    const unsigned short* __restrict__ kt,
    const unsigned short* __restrict__ vt,
    unsigned short* __restrict__ attnb)
{
  const int tid = threadIdx.x;
  const int w = tid >> 6, l = tid & 63;
  const int ln = l & 15, qu = l >> 4;
  const int sr = l >> 3, kbl = l & 7;
  const int bid = blockIdx.x;
  const int hd = bid % 192;                  // (co,b,h)
  const int q0 = (bid / 192) * 256;
  const int co = hd >> 6;
  const int b  = (hd >> 3) & 7;
  const int h  = hd & 7;
  const int cq = (co + 1) % 3, ckv = (co + 2) % 3;
  const unsigned short* Qg = qt + ((size_t)((cq  * 8 + b) * 8 + h) << 16);
  const unsigned short* Kg = kt + ((size_t)((ckv * 8 + b) * 8 + h) << 16);
  const unsigned short* Vg = vt + ((size_t)((ckv * 8 + b) * 8 + h) << 16);

  __shared__ unsigned short Ks[128 * 64];    // [key][d] swizzled, 16KB
  __shared__ unsigned short Vs[2][64 * 64];  // two [d][key] sub-tiles, 16KB

  short8v qf[2][2];
#pragma unroll
  for (int nt = 0; nt < 2; ++nt)
#pragma unroll
    for (int ks = 0; ks < 2; ++ks)
      qf[nt][ks] = *(const short8v*)&Qg[(size_t)(q0 + w * 32 + nt * 16 + ln) * 64 + ks * 32 + qu * 8];

  short8v onesf;
#pragma unroll
  for (int i = 0; i < 8; ++i) onesf[i] = (short)0x3F80;   // bf16 1.0
  const float4v zf = (float4v){0.f, 0.f, 0.f, 0.f};

  float4v acc_o[4][2];
#pragma unroll
  for (int i = 0; i < 4; ++i)
#pragma unroll
    for (int j = 0; j < 2; ++j) acc_o[i][j] = (float4v){0.f, 0.f, 0.f, 0.f};
  float4v acc_l[2];
  acc_l[0] = zf;
  acc_l[1] = zf;

  for (int kt0 = 0; kt0 < NCK; kt0 += 128) {
    __syncthreads();                         // all waves done with prev tile
    {
      int rK = w * 16;                       // 16 K-rows per wave (2 issues)
      gld_lds16(&Kg[(size_t)(kt0 + rK + sr) * 64 + ((kbl ^ sr) * 8)],
                &Ks[rK * 64]);
      gld_lds16(&Kg[(size_t)(kt0 + rK + 8 + sr) * 64 + ((kbl ^ sr) * 8)],
                &Ks[(rK + 8) * 64]);
      int rV = w * 8;                        // 8 d-rows per wave per sub-tile
      gld_lds16(&Vg[(size_t)(rV + sr) * 1024 + kt0 + ((kbl ^ sr) * 8)],
                &Vs[0][rV * 64]);
      gld_lds16(&Vg[(size_t)(rV + sr) * 1024 + kt0 + 64 + ((kbl ^ sr) * 8)],
                &Vs[1][rV * 64]);
    }
    __syncthreads();                         // vmcnt(0): tile staged

#pragma unroll
    for (int sub = 0; sub < 2; ++sub) {
      const int sub64 = sub * 64;

      // S-phase: S^T[key][q]; ks=0 writes via literal-zero C (exact)
      float4v sacc[4][2];
      __builtin_amdgcn_s_setprio(1);
#pragma unroll
      for (int mt = 0; mt < 4; ++mt) {
        int key = sub64 + 16 * mt + ln;
        short8v kf = *(const short8v*)&Ks[key * 64 + ((qu ^ (key & 7)) * 8)];
        sacc[mt][0] = MFMA(kf, qf[0][0], zf);
        sacc[mt][1] = MFMA(kf, qf[1][0], zf);
      }
#pragma unroll
      for (int mt = 0; mt < 4; ++mt) {
        int key = sub64 + 16 * mt + ln;
        short8v kf = *(const short8v*)&Ks[key * 64 + (((4 + qu) ^ (key & 7)) * 8)];
        sacc[mt][0] = MFMA(kf, qf[0][1], sacc[mt][0]);
        sacc[mt][1] = MFMA(kf, qf[1][1], sacc[mt][1]);
      }
      __builtin_amdgcn_s_setprio(0);

      // per 32-key half: exp2 -> pack2r -> permlane transpose -> denom + PV
#pragma unroll
      for (int ks2 = 0; ks2 < 2; ++ks2) {
        short8v pf[2];
#pragma unroll
        for (int nt = 0; nt < 2; ++nt) {
          float4v s0v = sacc[2 * ks2][nt];      // mh=0: keys 16*2ks2 + 4qu + r
          float4v s1v = sacc[2 * ks2 + 1][nt];  // mh=1: keys 16*(2ks2+1)+4qu+r
          float a0 = __builtin_amdgcn_exp2f(s0v[0]);
          float a1 = __builtin_amdgcn_exp2f(s0v[1]);
          float a2 = __builtin_amdgcn_exp2f(s0v[2]);
          float a3 = __builtin_amdgcn_exp2f(s0v[3]);
          float b0 = __builtin_amdgcn_exp2f(s1v[0]);
          float b1 = __builtin_amdgcn_exp2f(s1v[1]);
          float b2 = __builtin_amdgcn_exp2f(s1v[2]);
          float b3 = __builtin_amdgcn_exp2f(s1v[3]);
          unsigned int m00 = pack2r(a0, a1);    // (mh0,p0)
          unsigned int m01 = pack2r(a2, a3);    // (mh0,p1)
          unsigned int m10 = pack2r(b0, b1);    // (mh1,p0)
          unsigned int m11 = pack2r(b2, b3);    // (mh1,p1)
          asm("v_permlane32_swap_b32 %0, %1" : "+v"(m00), "+v"(m10));
          asm("v_permlane32_swap_b32 %0, %1" : "+v"(m01), "+v"(m11));
          asm("v_permlane16_swap_b32 %0, %1" : "+v"(m00), "+v"(m10));
          asm("v_permlane16_swap_b32 %0, %1" : "+v"(m01), "+v"(m11));
          uint4v t; t[0] = m00; t[1] = m01; t[2] = m10; t[3] = m11;
          pf[nt] = __builtin_bit_cast(short8v, t);
        }
        __builtin_amdgcn_s_setprio(1);
#pragma unroll
        for (int nt = 0; nt < 2; ++nt)
          acc_l[nt] = MFMA(onesf, pf[nt], acc_l[nt]);   // row-sum of P
#pragma unroll
        for (int mt2 = 0; mt2 < 4; ++mt2) {
          int dd = 16 * mt2 + ln;
          short8v vf = *(const short8v*)&Vs[sub][dd * 64 + (((ks2 * 4 + qu) ^ (dd & 7)) * 8)];
#pragma unroll
          for (int nt = 0; nt < 2; ++nt)
            acc_o[mt2][nt] = MFMA(vf, pf[nt], acc_o[mt2][nt]);
        }
        __builtin_amdgcn_s_setprio(0);
      }
    }
  }

  float inv[2];
  inv[0] = 1.0f / acc_l[0][0];
  inv[1] = 1.0f / acc_l[1][0];
  unsigned short* Og = attnb + (size_t)((co * 8 + b)) * NCK * EMB + h * HD;
#pragma unroll
  for (int mt = 0; mt < 4; ++mt) {
    int dd0 = 16 * mt + 4 * qu;
#pragma unroll
    for (int nt = 0; nt < 2; ++nt) {
      int q_glob = q0 + w * 32 + nt * 16 + ln;
      ushort4v p;
#pragma unroll
      for (int r = 0; r < 4; ++r) p[r] = f2b(acc_o[mt][nt][r] * inv[nt]);
      *(ushort4v*)&Og[(size_t)q_glob * EMB + dd0] = p;
    }
  }
}

// ---------------- Output projection ----------------
// 256x128 tile (tokens x f), BK=64, 8 waves — same R18 structure as qkv.
// 1D grid 384, T1 XCD-chunk swizzle: lin=(bid&7)*48+bid/8; col0=(lin&3)*128,
// row0=(lin>>2)*256 -> 4 attnb-panel sharers consecutive.
// D = Wp·A^T -> [f][token]; fp32 float4 stores.
__global__ __launch_bounds__(512, 4) void proj_gemm(
    const unsigned short* __restrict__ attnb,
    const unsigned short* __restrict__ Wpb, const float* __restrict__ bp,
    float* __restrict__ out)
{
  const int tid = threadIdx.x;
  const int w = tid >> 6, l = tid & 63;
  const int ln = l & 15, qu = l >> 4;
  const int sr = l >> 3, kbl = l & 7;
  const int bid = blockIdx.x;
  const int lin = (bid & 7) * 48 + (bid >> 3);
  const int col0 = (lin & 3) * 128;
  const int row0 = (lin >> 2) * 256;          // [c][b][n] rows
  const int c = row0 >> 13;
  const int bglob = (row0 >> 10) & 7;
  const int n0 = row0 & 1023;
  const unsigned short* W = Wpb + c * EMB * EMB;
  const float* bias = bp + c * EMB;

  __shared__ unsigned short As[256 * 64];
  __shared__ unsigned short Bs[128 * 64];

  const int xo = (w & 3) * 64, fo = (w >> 2) * 64;

  float4v acc[4][4];
#pragma unroll
  for (int i = 0; i < 4; ++i)
#pragma unroll
    for (int j = 0; j < 4; ++j) acc[i][j] = (float4v){0.f, 0.f, 0.f, 0.f};

  for (int k0 = 0; k0 < EMB; k0 += 64) {
    __syncthreads();
    {
      int kb_g = kbl ^ sr;
#pragma unroll
      for (int s = 0; s < 4; ++s) {          // As: 256 rows
        int rbase = w * 32 + s * 8;
        gld_lds16(&attnb[(size_t)(row0 + rbase + sr) * EMB + k0 + kb_g * 8],
                  &As[rbase * 64]);
      }
#pragma unroll
      for (int s = 0; s < 2; ++s) {          // Bs: 128 rows
        int rbase = w * 16 + s * 8;
        gld_lds16(&W[(size_t)(col0 + rbase + sr) * EMB + k0 + kb_g * 8],
                  &Bs[rbase * 64]);
      }
    }
    __syncthreads();
#pragma unroll
    for (int ks = 0; ks < 2; ++ks) {
      short8v xf[4], wf[4];
#pragma unroll
      for (int i = 0; i < 4; ++i) {
        int rx = xo + 16 * i + ln;
        xf[i] = *(const short8v*)&As[rx * 64 + (((ks * 4 + qu) ^ (rx & 7)) * 8)];
        int rw = fo + 16 * i + ln;
        wf[i] = *(const short8v*)&Bs[rw * 64 + (((ks * 4 + qu) ^ (rw & 7)) * 8)];
      }
#pragma unroll
      for (int i = 0; i < 4; ++i)
#pragma unroll
        for (int j = 0; j < 4; ++j) acc[i][j] = MFMA(wf[j], xf[i], acc[i][j]);
    }
  }

#pragma unroll
  for (int j = 0; j < 4; ++j) {              // f (M side)
    int f0 = col0 + fo + 16 * j + 4 * qu;    // + r
    float4 b4 = *(const float4*)&bias[f0];
#pragma unroll
    for (int i = 0; i < 4; ++i) {            // token (N side)
      int srow = bglob * SEQ + c * NCK + n0 + xo + 16 * i + ln;
      float4 o;
      o.x = acc[i][j][0] + b4.x;
      o.y = acc[i][j][1] + b4.y;
      o.z = acc[i][j][2] + b4.z;
      o.w = acc[i][j][3] + b4.w;
      *(float4*)&out[(size_t)srow * EMB + f0] = o;
    }
  }
}

extern "C" void kernel_launch(void* const* d_in, const int* in_sizes, int n_in,
                              void* d_out, int out_size, void* d_ws, size_t ws_size,
                              hipStream_t stream) {
  (void)in_sizes; (void)n_in; (void)out_size; (void)ws_size;
  const float* x  = (const float*)d_in[0];
  const float* Wq = (const float*)d_in[1];
  const float* bq = (const float*)d_in[2];
  const float* Wk = (const float*)d_in[3];
  const float* bk = (const float*)d_in[4];
  const float* Wv = (const float*)d_in[5];
  const float* bv = (const float*)d_in[6];
  const float* Wp = (const float*)d_in[7];
  const float* bp = (const float*)d_in[8];
  float* out = (float*)d_out;

  // workspace layout (bf16 elems): [Wb 4*WELEMS][qt][kt][vt][attn(=x_bf)]
  // = 6.3 MB + 4*25.2 MB = 107 MB. x_bf aliases the attn slot: x_bf is only
  // read by qkv_gemm, which completes before attn_kernel writes attnb.
  unsigned short* Wb   = (unsigned short*)d_ws;
  unsigned short* qt   = Wb + 4 * (size_t)WELEMS;
  unsigned short* kt   = qt + QKV_ELEMS;
  unsigned short* vt   = kt + QKV_ELEMS;
  unsigned short* attn = vt + QKV_ELEMS;
  unsigned short* xbf  = attn;  // alias (see above)

  conv_all<<<XCONV_BLOCKS + 4 * WCONV_BLOCKS, 256, 0, stream>>>(
      x, Wq, Wk, Wv, Wp, xbf, Wb);
  qkv_gemm<<<(MTOT / 256) * (EMB / 128) * 3, 512, 0, stream>>>(
      xbf, Wb, bq, bk, bv, qt, kt, vt);
  attn_kernel<<<(NCK / 256) * CHUNKS * BATCH * NH, 512, 0, stream>>>(qt, kt, vt, attn);
  proj_gemm<<<(MTOT / 256) * (EMB / 128), 512, 0, stream>>>(attn, Wb + 3 * (size_t)WELEMS, bp, out);
}

// Round 14
// 254.706 us; speedup vs baseline: 2.4048x; 2.4048x over previous
//
#include <hip/hip_runtime.h>
#include <hip/hip_bf16.h>

// CSMultiHeadAttention. B=8, S=3072 (3x1024), E=512, H=8, d=64.
// fp32 I/O, bf16 workspace, fp32 MFMA accumulate.
// R7-R15 (VERIFIED, 256.0us): attn in-reg P (permlane transpose), T5 setprio,
//   KVBLK=128 single-buffer; qkv/proj 128x128 single-buffer + T1 XCD swizzle.
// R16 (VERIFIED, 252.2us): conv merged to one launch; boundary cost ~3.8us.
// R18 FAILED (612us): qkv/proj 256x128 with __launch_bounds__(512,4) ->
//   128-reg cap on unified VGPR file < ~130 live -> acc spilled to scratch
//   (VGPR_Count 64, WRITE 1.24GB, MfmaUtil 3.7%). Without the cap the shape
//   needs ~132 regs -> 1 block/CU (occupancy cliff via registers). The
//   128^2 / 4-wave / ~124-reg shape is a local optimum pinned by the
//   512-reg file: 4 waves/SIMD -> 4 blocks/CU. DO NOT enlarge tiles here.
// R19 (this round): exact revert to the R16 build (252.2us verified).
// MFMA 16x16x32 bf16. A/B frag: [m|n = lane&15][k = (lane>>4)*8 + j].
// C/D: col = lane&15, row = (lane>>4)*4 + reg.
// GEMM LDS tiles XOR-swizzled (block kb ^ (row&7)): free 2-way banks AND
// matches global_load_lds lane-contiguous destination.

typedef __attribute__((ext_vector_type(8))) short short8v;     // 8 bf16 (4 VGPR)
typedef __attribute__((ext_vector_type(4))) float float4v;
typedef __attribute__((ext_vector_type(4))) unsigned short ushort4v;
typedef __attribute__((ext_vector_type(4))) unsigned int uint4v;

#define CHUNKS 3
#define BATCH 8
#define SEQ 3072
#define EMB 512
#define NH 8
#define HD 64
#define NCK 1024
#define MTOT (BATCH*SEQ)                      // 24576
#define QKV_ELEMS (CHUNKS*BATCH*NH*NCK*HD)    // 12582912 (== x elem count)
#define WELEMS (CHUNKS*EMB*EMB)               // 786432 per weight tensor
#define XCONV_BLOCKS (QKV_ELEMS / (256 * 8))  // 6144
#define WCONV_BLOCKS (WELEMS / (256 * 8))     // 384 per weight tensor
// 1/sqrt(512) * log2(e): softmax exp folded to exp2
#define QSCALE 0.06375872465f

__device__ __forceinline__ unsigned short f2b(float f) {
  union { float f; unsigned int i; } x; x.f = f;
  unsigned int r = x.i + 0x7FFFu + ((x.i >> 16) & 1u);  // RNE
  return (unsigned short)(r >> 16);
}
// pack two fp32 -> two bf16 (round-half-up) in 3 VALU via v_perm
__device__ __forceinline__ unsigned int pack2r(float a, float b) {
  union { float f; unsigned int u; } xa, xb; xa.f = a; xb.f = b;
  return __builtin_amdgcn_perm(xb.u + 0x8000u, xa.u + 0x8000u, 0x07060302u);
}
__device__ __forceinline__ void gld_lds16(const unsigned short* g, unsigned short* l) {
  __builtin_amdgcn_global_load_lds(
      (const __attribute__((address_space(1))) unsigned int*)g,
      (__attribute__((address_space(3))) unsigned int*)l, 16, 0, 0);
}
#define MFMA(a, b, c) __builtin_amdgcn_mfma_f32_16x16x32_bf16(a, b, c, 0, 0, 0)

// ---------------- fp32 -> bf16 conversion (streaming, single launch) -------
// Blocks [0, XCONV_BLOCKS): convert x -> xbf.
// Blocks [XCONV_BLOCKS, +4*WCONV_BLOCKS): convert Wq/Wk/Wv/Wp -> Wb.
__global__ __launch_bounds__(256) void conv_all(
    const float* __restrict__ x,
    const float* __restrict__ s0, const float* __restrict__ s1,
    const float* __restrict__ s2, const float* __restrict__ s3,
    unsigned short* __restrict__ xbf, unsigned short* __restrict__ Wb)
{
  const int bid = blockIdx.x;
  const float* src;
  unsigned short* dst;
  size_t i;
  if (bid < XCONV_BLOCKS) {
    i = ((size_t)bid * 256 + threadIdx.x) * 8;
    src = x;
    dst = xbf;
  } else {
    const int wb = bid - XCONV_BLOCKS;
    const int z = wb / WCONV_BLOCKS;
    i = ((size_t)(wb % WCONV_BLOCKS) * 256 + threadIdx.x) * 8;
    src = (z == 0) ? s0 : (z == 1) ? s1 : (z == 2) ? s2 : s3;
    dst = Wb + (size_t)z * WELEMS;
  }
  float4 a = *(const float4*)&src[i];
  float4 b = *(const float4*)&src[i + 4];
  uint4v p;
  p[0] = pack2r(a.x, a.y); p[1] = pack2r(a.z, a.w);
  p[2] = pack2r(b.x, b.y); p[3] = pack2r(b.z, b.w);
  *(uint4v*)&dst[i] = p;
}

// ---------------- QKV projection ----------------
// 128x128 tile, BK=64, 4 waves; wave w: x-rows xo=(w&1)*64, f-cols fo=(w>>1)*64.
// Single-buffered. 1D grid 2304, T1 XCD-chunk swizzle (VERIFIED R9):
// lin = (bid&7)*288 + bid/8; col0=(lin&3)*128, z=(lin>>2)%3, row0=(lin/12)*128.
// Blocks sharing an x-panel (4 col x 3 z) consecutive within an XCD chunk.
// z<=1 (Q,K): D = W·X^T -> [f][token] -> packed b64 stores along d into [n][d].
//             Q is additionally scaled by QSCALE (softmax scale * log2e).
// z==2 (V):   D = X·W^T -> [token][f] -> packed b64 stores along n into [d][n].
__global__ __launch_bounds__(256) void qkv_gemm(
    const unsigned short* __restrict__ xb, const unsigned short* __restrict__ Wb,
    const float* __restrict__ bq, const float* __restrict__ bk,
    const float* __restrict__ bv,
    unsigned short* __restrict__ qt, unsigned short* __restrict__ kt,
    unsigned short* __restrict__ vt)
{
  const int tid = threadIdx.x;
  const int w = tid >> 6, l = tid & 63;
  const int ln = l & 15, qu = l >> 4;
  const int sr = l >> 3, kbl = l & 7;
  const int bid = blockIdx.x;
  const int lin = (bid & 7) * 288 + (bid >> 3);
  const int col0 = (lin & 3) * 128;
  const int z = (lin >> 2) % 3;
  const int row0 = (lin / 12) * 128;
  const int bglob = row0 / SEQ;
  const int c = (row0 % SEQ) / NCK;
  const int n0 = row0 % NCK;
  const unsigned short* W = Wb + (size_t)z * WELEMS + c * EMB * EMB;
  const float* bias = (z == 0 ? bq : (z == 1 ? bk : bv)) + c * EMB;
  const float oscale = (z == 0) ? QSCALE : 1.0f;

  __shared__ unsigned short As[128 * 64];   // x-tile, swizzled
  __shared__ unsigned short Bs[128 * 64];   // W-tile, swizzled

  const int xo = (w & 1) * 64, fo = (w >> 1) * 64;

  float4v acc[4][4];
#pragma unroll
  for (int i = 0; i < 4; ++i)
#pragma unroll
    for (int j = 0; j < 4; ++j) acc[i][j] = (float4v){0.f, 0.f, 0.f, 0.f};

  for (int k0 = 0; k0 < EMB; k0 += 64) {
    __syncthreads();
#pragma unroll
    for (int s = 0; s < 4; ++s) {
      int rbase = w * 32 + s * 8;
      int r = rbase + sr;                    // per-lane global row
      int kb_g = kbl ^ sr;                   // swizzled k-block
      gld_lds16(&xb[(size_t)(row0 + r) * EMB + k0 + kb_g * 8], &As[rbase * 64]);
      gld_lds16(&W [(size_t)(col0 + r) * EMB + k0 + kb_g * 8], &Bs[rbase * 64]);
    }
    __syncthreads();
#pragma unroll
    for (int ks = 0; ks < 2; ++ks) {
      short8v xf[4], wf[4];
#pragma unroll
      for (int i = 0; i < 4; ++i) {
        int rx = xo + 16 * i + ln;
        xf[i] = *(const short8v*)&As[rx * 64 + (((ks * 4 + qu) ^ (rx & 7)) * 8)];
        int rw = fo + 16 * i + ln;
        wf[i] = *(const short8v*)&Bs[rw * 64 + (((ks * 4 + qu) ^ (rw & 7)) * 8)];
      }
      if (z <= 1) {
#pragma unroll
        for (int i = 0; i < 4; ++i)
#pragma unroll
          for (int j = 0; j < 4; ++j) acc[i][j] = MFMA(wf[j], xf[i], acc[i][j]);
      } else {
#pragma unroll
        for (int i = 0; i < 4; ++i)
#pragma unroll
          for (int j = 0; j < 4; ++j) acc[i][j] = MFMA(xf[i], wf[j], acc[i][j]);
      }
    }
  }

  if (z <= 1) {
    unsigned short* outp = (z == 0) ? qt : kt;
#pragma unroll
    for (int j = 0; j < 4; ++j) {            // f (M side)
      int f0 = col0 + fo + 16 * j + 4 * qu;  // + r
      float4 b4 = *(const float4*)&bias[f0];
      int hh = f0 >> 6, dd0 = f0 & 63;
      size_t base = ((size_t)((c * 8 + bglob) * 8 + hh)) << 16;
#pragma unroll
      for (int i = 0; i < 4; ++i) {          // token (N side)
        int n = n0 + xo + 16 * i + ln;
        ushort4v p;
#pragma unroll
        for (int r = 0; r < 4; ++r)
          p[r] = f2b((acc[i][j][r] + ((const float*)&b4)[r]) * oscale);
        *(ushort4v*)&outp[base + (size_t)n * 64 + dd0] = p;
      }
    }
  } else {
#pragma unroll
    for (int i = 0; i < 4; ++i) {            // token (M side)
      int nn0 = n0 + xo + 16 * i + 4 * qu;   // + r
#pragma unroll
      for (int j = 0; j < 4; ++j) {          // f (N side)
        int f = col0 + fo + 16 * j + ln;
        int hh = f >> 6, dd = f & 63;
        float bvv = bias[f];
        size_t base = ((size_t)((c * 8 + bglob) * 8 + hh)) << 16;
        ushort4v p;
#pragma unroll
        for (int r = 0; r < 4; ++r) p[r] = f2b(acc[i][j][r] + bvv);
        *(ushort4v*)&vt[base + (size_t)dd * 1024 + nn0] = p;
      }
    }
  }
}

// ---------------- Attention (flash, MFMA) ----------------
// 512 threads / 8 waves / 256 q rows per block; 4 q-blocks per head.
// SINGLE-buffered, KVBLK=128 (VERIFIED 69.4us): one barrier pair stages 128
// keys (Ks[128][64], Vs[2][64][64], 32KB), then TWO 64-key sub-passes.
// Per sub-pass: S^T = K·Q^T (ks=0 literal-zero C); per 32-key half: exp2 ->
// pack2r -> permlane 4x4 transpose -> denom(ones-MFMA) + O^T += V^T·P^T.
// Q pre-scaled by 1/sqrt(512)*log2e in qkv -> raw v_exp_f32 here.
// setprio(1) wraps MFMA clusters (T5).
//
// P redistribution: S^T C/D gives lane(ln,qu) S[q=ln][key=16mt+4qu+r];
// PV B-frag needs P[q=ln][key=8qu+j]. permlane32_swap x2 (l5<->mh) then
// permlane16_swap x2 (l4<->old l5); frag = [m00,m01,m10,m11].
// (VERIFIED on HW: absmax 4.9e-4.)
__global__ __launch_bounds__(512) void attn_kernel(
    const unsigned short* __restrict__ qt,
    const unsigned short* __restrict__ kt,
    const unsigned short* __restrict__ vt,
    unsigned short* __restrict__ attnb)
{
  const int tid = threadIdx.x;
  const int w = tid >> 6, l = tid & 63;
  const int ln = l & 15, qu = l >> 4;
  const int sr = l >> 3, kbl = l & 7;
  const int bid = blockIdx.x;
  const int hd = bid % 192;                  // (co,b,h)
  const int q0 = (bid / 192) * 256;
  const int co = hd >> 6;
  const int b  = (hd >> 3) & 7;
  const int h  = hd & 7;
  const int cq = (co + 1) % 3, ckv = (co + 2) % 3;
  const unsigned short* Qg = qt + ((size_t)((cq  * 8 + b) * 8 + h) << 16);
  const unsigned short* Kg = kt + ((size_t)((ckv * 8 + b) * 8 + h) << 16);
  const unsigned short* Vg = vt + ((size_t)((ckv * 8 + b) * 8 + h) << 16);

  __shared__ unsigned short Ks[128 * 64];    // [key][d] swizzled, 16KB
  __shared__ unsigned short Vs[2][64 * 64];  // two [d][key] sub-tiles, 16KB

  short8v qf[2][2];
#pragma unroll
  for (int nt = 0; nt < 2; ++nt)
#pragma unroll
    for (int ks = 0; ks < 2; ++ks)
      qf[nt][ks] = *(const short8v*)&Qg[(size_t)(q0 + w * 32 + nt * 16 + ln) * 64 + ks * 32 + qu * 8];

  short8v onesf;
#pragma unroll
  for (int i = 0; i < 8; ++i) onesf[i] = (short)0x3F80;   // bf16 1.0
  const float4v zf = (float4v){0.f, 0.f, 0.f, 0.f};

  float4v acc_o[4][2];
#pragma unroll
  for (int i = 0; i < 4; ++i)
#pragma unroll
    for (int j = 0; j < 2; ++j) acc_o[i][j] = (float4v){0.f, 0.f, 0.f, 0.f};
  float4v acc_l[2];
  acc_l[0] = zf;
  acc_l[1] = zf;

  for (int kt0 = 0; kt0 < NCK; kt0 += 128) {
    __syncthreads();                         // all waves done with prev tile
    {
      int rK = w * 16;                       // 16 K-rows per wave (2 issues)
      gld_lds16(&Kg[(size_t)(kt0 + rK + sr) * 64 + ((kbl ^ sr) * 8)],
                &Ks[rK * 64]);
      gld_lds16(&Kg[(size_t)(kt0 + rK + 8 + sr) * 64 + ((kbl ^ sr) * 8)],
                &Ks[(rK + 8) * 64]);
      int rV = w * 8;                        // 8 d-rows per wave per sub-tile
      gld_lds16(&Vg[(size_t)(rV + sr) * 1024 + kt0 + ((kbl ^ sr) * 8)],
                &Vs[0][rV * 64]);
      gld_lds16(&Vg[(size_t)(rV + sr) * 1024 + kt0 + 64 + ((kbl ^ sr) * 8)],
                &Vs[1][rV * 64]);
    }
    __syncthreads();                         // vmcnt(0): tile staged

#pragma unroll
    for (int sub = 0; sub < 2; ++sub) {
      const int sub64 = sub * 64;

      // S-phase: S^T[key][q]; ks=0 writes via literal-zero C (exact)
      float4v sacc[4][2];
      __builtin_amdgcn_s_setprio(1);
#pragma unroll
      for (int mt = 0; mt < 4; ++mt) {
        int key = sub64 + 16 * mt + ln;
        short8v kf = *(const short8v*)&Ks[key * 64 + ((qu ^ (key & 7)) * 8)];
        sacc[mt][0] = MFMA(kf, qf[0][0], zf);
        sacc[mt][1] = MFMA(kf, qf[1][0], zf);
      }
#pragma unroll
      for (int mt = 0; mt < 4; ++mt) {
        int key = sub64 + 16 * mt + ln;
        short8v kf = *(const short8v*)&Ks[key * 64 + (((4 + qu) ^ (key & 7)) * 8)];
        sacc[mt][0] = MFMA(kf, qf[0][1], sacc[mt][0]);
        sacc[mt][1] = MFMA(kf, qf[1][1], sacc[mt][1]);
      }
      __builtin_amdgcn_s_setprio(0);

      // per 32-key half: exp2 -> pack2r -> permlane transpose -> denom + PV
#pragma unroll
      for (int ks2 = 0; ks2 < 2; ++ks2) {
        short8v pf[2];
#pragma unroll
        for (int nt = 0; nt < 2; ++nt) {
          float4v s0v = sacc[2 * ks2][nt];      // mh=0: keys 16*2ks2 + 4qu + r
          float4v s1v = sacc[2 * ks2 + 1][nt];  // mh=1: keys 16*(2ks2+1)+4qu+r
          float a0 = __builtin_amdgcn_exp2f(s0v[0]);
          float a1 = __builtin_amdgcn_exp2f(s0v[1]);
          float a2 = __builtin_amdgcn_exp2f(s0v[2]);
          float a3 = __builtin_amdgcn_exp2f(s0v[3]);
          float b0 = __builtin_amdgcn_exp2f(s1v[0]);
          float b1 = __builtin_amdgcn_exp2f(s1v[1]);
          float b2 = __builtin_amdgcn_exp2f(s1v[2]);
          float b3 = __builtin_amdgcn_exp2f(s1v[3]);
          unsigned int m00 = pack2r(a0, a1);    // (mh0,p0)
          unsigned int m01 = pack2r(a2, a3);    // (mh0,p1)
          unsigned int m10 = pack2r(b0, b1);    // (mh1,p0)
          unsigned int m11 = pack2r(b2, b3);    // (mh1,p1)
          asm("v_permlane32_swap_b32 %0, %1" : "+v"(m00), "+v"(m10));
          asm("v_permlane32_swap_b32 %0, %1" : "+v"(m01), "+v"(m11));
          asm("v_permlane16_swap_b32 %0, %1" : "+v"(m00), "+v"(m10));
          asm("v_permlane16_swap_b32 %0, %1" : "+v"(m01), "+v"(m11));
          uint4v t; t[0] = m00; t[1] = m01; t[2] = m10; t[3] = m11;
          pf[nt] = __builtin_bit_cast(short8v, t);
        }
        __builtin_amdgcn_s_setprio(1);
#pragma unroll
        for (int nt = 0; nt < 2; ++nt)
          acc_l[nt] = MFMA(onesf, pf[nt], acc_l[nt]);   // row-sum of P
#pragma unroll
        for (int mt2 = 0; mt2 < 4; ++mt2) {
          int dd = 16 * mt2 + ln;
          short8v vf = *(const short8v*)&Vs[sub][dd * 64 + (((ks2 * 4 + qu) ^ (dd & 7)) * 8)];
#pragma unroll
          for (int nt = 0; nt < 2; ++nt)
            acc_o[mt2][nt] = MFMA(vf, pf[nt], acc_o[mt2][nt]);
        }
        __builtin_amdgcn_s_setprio(0);
      }
    }
  }

  float inv[2];
  inv[0] = 1.0f / acc_l[0][0];
  inv[1] = 1.0f / acc_l[1][0];
  unsigned short* Og = attnb + (size_t)((co * 8 + b)) * NCK * EMB + h * HD;
#pragma unroll
  for (int mt = 0; mt < 4; ++mt) {
    int dd0 = 16 * mt + 4 * qu;
#pragma unroll
    for (int nt = 0; nt < 2; ++nt) {
      int q_glob = q0 + w * 32 + nt * 16 + ln;
      ushort4v p;
#pragma unroll
      for (int r = 0; r < 4; ++r) p[r] = f2b(acc_o[mt][nt][r] * inv[nt]);
      *(ushort4v*)&Og[(size_t)q_glob * EMB + dd0] = p;
    }
  }
}

// ---------------- Output projection ----------------
// A = attnb (bf16), B = Wp_bf (bf16): both via global_load_lds, single-buffer.
// 1D grid 768, T1 XCD-chunk swizzle (VERIFIED R9): lin=(bid&7)*96+bid/8;
// col0=(lin&3)*128, row0=(lin>>2)*128 -> 4 attnb-panel sharers consecutive.
// D = Wp·A^T -> [f][token]; fp32 float4 stores.
__global__ __launch_bounds__(256) void proj_gemm(
    const unsigned short* __restrict__ attnb,
    const unsigned short* __restrict__ Wpb, const float* __restrict__ bp,
    float* __restrict__ out)
{
  const int tid = threadIdx.x;
  const int w = tid >> 6, l = tid & 63;
  const int ln = l & 15, qu = l >> 4;
  const int sr = l >> 3, kbl = l & 7;
  const int bid = blockIdx.x;
  const int lin = (bid & 7) * 96 + (bid >> 3);
  const int col0 = (lin & 3) * 128;
  const int row0 = (lin >> 2) * 128;          // [c][b][n] rows
  const int c = row0 >> 13;
  const int bglob = (row0 >> 10) & 7;
  const int n0 = row0 & 1023;
  const unsigned short* W = Wpb + c * EMB * EMB;
  const float* bias = bp + c * EMB;

  __shared__ unsigned short As[128 * 64];
  __shared__ unsigned short Bs[128 * 64];

  const int xo = (w & 1) * 64, fo = (w >> 1) * 64;

  float4v acc[4][4];
#pragma unroll
  for (int i = 0; i < 4; ++i)
#pragma unroll
    for (int j = 0; j < 4; ++j) acc[i][j] = (float4v){0.f, 0.f, 0.f, 0.f};

  for (int k0 = 0; k0 < EMB; k0 += 64) {
    __syncthreads();
#pragma unroll
    for (int s = 0; s < 4; ++s) {
      int rbase = w * 32 + s * 8;
      int r = rbase + sr;
      int kb_g = kbl ^ sr;
      gld_lds16(&attnb[(size_t)(row0 + r) * EMB + k0 + kb_g * 8], &As[rbase * 64]);
      gld_lds16(&W    [(size_t)(col0 + r) * EMB + k0 + kb_g * 8], &Bs[rbase * 64]);
    }
    __syncthreads();
#pragma unroll
    for (int ks = 0; ks < 2; ++ks) {
      short8v xf[4], wf[4];
#pragma unroll
      for (int i = 0; i < 4; ++i) {
        int rx = xo + 16 * i + ln;
        xf[i] = *(const short8v*)&As[rx * 64 + (((ks * 4 + qu) ^ (rx & 7)) * 8)];
        int rw = fo + 16 * i + ln;
        wf[i] = *(const short8v*)&Bs[rw * 64 + (((ks * 4 + qu) ^ (rw & 7)) * 8)];
      }
#pragma unroll
      for (int i = 0; i < 4; ++i)
#pragma unroll
        for (int j = 0; j < 4; ++j) acc[i][j] = MFMA(wf[j], xf[i], acc[i][j]);
    }
  }

#pragma unroll
  for (int j = 0; j < 4; ++j) {              // f (M side)
    int f0 = col0 + fo + 16 * j + 4 * qu;    // + r
    float4 b4 = *(const float4*)&bias[f0];
#pragma unroll
    for (int i = 0; i < 4; ++i) {            // token (N side)
      int srow = bglob * SEQ + c * NCK + n0 + xo + 16 * i + ln;
      float4 o;
      o.x = acc[i][j][0] + b4.x;
      o.y = acc[i][j][1] + b4.y;
      o.z = acc[i][j][2] + b4.z;
      o.w = acc[i][j][3] + b4.w;
      *(float4*)&out[(size_t)srow * EMB + f0] = o;
    }
  }
}

extern "C" void kernel_launch(void* const* d_in, const int* in_sizes, int n_in,
                              void* d_out, int out_size, void* d_ws, size_t ws_size,
                              hipStream_t stream) {
  (void)in_sizes; (void)n_in; (void)out_size; (void)ws_size;
  const float* x  = (const float*)d_in[0];
  const float* Wq = (const float*)d_in[1];
  const float* bq = (const float*)d_in[2];
  const float* Wk = (const float*)d_in[3];
  const float* bk = (const float*)d_in[4];
  const float* Wv = (const float*)d_in[5];
  const float* bv = (const float*)d_in[6];
  const float* Wp = (const float*)d_in[7];
  const float* bp = (const float*)d_in[8];
  float* out = (float*)d_out;

  // workspace layout (bf16 elems): [Wb 4*WELEMS][qt][kt][vt][attn(=x_bf)]
  // = 6.3 MB + 4*25.2 MB = 107 MB. x_bf aliases the attn slot: x_bf is only
  // read by qkv_gemm, which completes before attn_kernel writes attnb.
  unsigned short* Wb   = (unsigned short*)d_ws;
  unsigned short* qt   = Wb + 4 * (size_t)WELEMS;
  unsigned short* kt   = qt + QKV_ELEMS;
  unsigned short* vt   = kt + QKV_ELEMS;
  unsigned short* attn = vt + QKV_ELEMS;
  unsigned short* xbf  = attn;  // alias (see above)

  conv_all<<<XCONV_BLOCKS + 4 * WCONV_BLOCKS, 256, 0, stream>>>(
      x, Wq, Wk, Wv, Wp, xbf, Wb);
  qkv_gemm<<<(MTOT / 128) * (EMB / 128) * 3, 256, 0, stream>>>(
      xbf, Wb, bq, bk, bv, qt, kt, vt);
  attn_kernel<<<(NCK / 256) * CHUNKS * BATCH * NH, 512, 0, stream>>>(qt, kt, vt, attn);
  proj_gemm<<<(MTOT / 128) * (EMB / 128), 256, 0, stream>>>(attn, Wb + 3 * (size_t)WELEMS, bp, out);
}